// Round 4
// baseline (2633.866 us; speedup 1.0000x reference)
//
#include <hip/hip_runtime.h>
#include <math.h>

#define NSTEPS 3000
#define NWALK  1048576
#define BLOCK  256
#define NBLOCKS 2048                    // 8 blocks/CU x 256 CU (VGPR<=64, LDS 16KB -> 8 resident)
#define NSTATIC (NBLOCKS * BLOCK)       // 524288 static walkers
#define NCTR   64                       // distributed steal counters
#define CTR_STRIDE 32                   // u32 stride -> 128 B apart (no same-line contention)
#define SUBRANGE ((NWALK - NSTATIC) / NCTR)   // 8192 walkers per counter
#define KLDS   2048                     // keys cached in LDS; P(t>=2048) ~ 1e-11, inline fallback

__device__ uint32_t g_ctrs[NCTR * CTR_STRIDE];

__global__ void init_ctrs_kernel() {
  g_ctrs[threadIdx.x * CTR_STRIDE] = 0u;   // <<<1,64>>>
}

// Threefry-2x32, 20 rounds, exactly JAX's schedule.
__device__ __forceinline__ void tf2x32(uint32_t k0, uint32_t k1,
                                       uint32_t x0, uint32_t x1,
                                       uint32_t& o0, uint32_t& o1) {
  uint32_t ks2 = k0 ^ k1 ^ 0x1BD11BDAu;
  x0 += k0; x1 += k1;
#define TFR(r) { x0 += x1; x1 = (x1 << r) | (x1 >> (32 - r)); x1 ^= x0; }
  TFR(13) TFR(15) TFR(26) TFR(6)
  x0 += k1;  x1 += ks2 + 1u;
  TFR(17) TFR(29) TFR(16) TFR(24)
  x0 += ks2; x1 += k0 + 2u;
  TFR(13) TFR(15) TFR(26) TFR(6)
  x0 += k0;  x1 += k1 + 3u;
  TFR(17) TFR(29) TFR(16) TFR(24)
  x0 += k1;  x1 += ks2 + 4u;
  TFR(13) TFR(15) TFR(26) TFR(6)
  x0 += ks2; x1 += k0 + 5u;
#undef TFR
  o0 = x0; o1 = x1;
}

// XLA CPU's log.f32 (Cephes/Eigen-3.3 plog), strict f32 mul/add, no FMA.
// Bit-exact vs reference (verified R3: absmax 0.094 << 0.259).
__device__ __forceinline__ float xla_cpu_log_f32(float s) {
  uint32_t bits = __float_as_uint(s);
  int emm0 = (int)(bits >> 23) - 0x7f;
  float e = __fadd_rn((float)emm0, 1.0f);
  float m = __uint_as_float((bits & 0x007fffffu) | 0x3f000000u);
  bool mlt = m < 0.70710677f;
  float tmp = mlt ? m : 0.0f;
  float x = __fsub_rn(m, 1.0f);
  e = __fsub_rn(e, mlt ? 1.0f : 0.0f);
  x = __fadd_rn(x, tmp);
  float x2 = __fmul_rn(x, x);
  float x3 = __fmul_rn(x2, x);
  float y, y1, y2;
  y  = __fadd_rn(__fmul_rn(7.0376836292e-2f,  x), -1.1514610310e-1f);
  y1 = __fadd_rn(__fmul_rn(-1.2420140846e-1f, x),  1.4249322787e-1f);
  y2 = __fadd_rn(__fmul_rn(2.0000714765e-1f,  x), -2.4999993993e-1f);
  y  = __fadd_rn(__fmul_rn(y,  x),  1.1676998740e-1f);
  y1 = __fadd_rn(__fmul_rn(y1, x), -1.6668057665e-1f);
  y2 = __fadd_rn(__fmul_rn(y2, x),  3.3333331174e-1f);
  y  = __fadd_rn(__fmul_rn(y, x3), y1);
  y  = __fadd_rn(__fmul_rn(y, x3), y2);
  y  = __fmul_rn(y, x3);
  y1 = __fmul_rn(e, -2.12194440e-4f);
  tmp = __fmul_rn(x2, 0.5f);
  y  = __fadd_rn(y, y1);
  x  = __fsub_rn(x, tmp);
  y2 = __fmul_rn(e, 0.693359375f);
  x  = __fadd_rn(x, y);
  x  = __fadd_rn(x, y2);
  return x;
}

// XLA EmitErfInv f32 (Giles): w = -log((1-x)*(1+x)), branch at w<5.
__device__ __forceinline__ float xla_erfinv_f32(float x) {
  float s = __fmul_rn(__fsub_rn(1.0f, x), __fadd_rn(1.0f, x));
  float w = -xla_cpu_log_f32(s);
  float p;
  if (w < 5.0f) {
    float v = __fsub_rn(w, 2.5f);
    p = 2.81022636e-08f;
    p = __fadd_rn(__fmul_rn(p, v), 3.43273939e-07f);
    p = __fadd_rn(__fmul_rn(p, v), -3.5233877e-06f);
    p = __fadd_rn(__fmul_rn(p, v), -4.39150654e-06f);
    p = __fadd_rn(__fmul_rn(p, v), 0.00021858087f);
    p = __fadd_rn(__fmul_rn(p, v), -0.00125372503f);
    p = __fadd_rn(__fmul_rn(p, v), -0.00417768164f);
    p = __fadd_rn(__fmul_rn(p, v), 0.246640727f);
    p = __fadd_rn(__fmul_rn(p, v), 1.50140941f);
  } else {
    float v = __fsub_rn(__fsqrt_rn(w), 3.0f);
    p = -0.000200214257f;
    p = __fadd_rn(__fmul_rn(p, v), 0.000100950558f);
    p = __fadd_rn(__fmul_rn(p, v), 0.00134934322f);
    p = __fadd_rn(__fmul_rn(p, v), -0.00367342844f);
    p = __fadd_rn(__fmul_rn(p, v), 0.00573950773f);
    p = __fadd_rn(__fmul_rn(p, v), -0.0076224613f);
    p = __fadd_rn(__fmul_rn(p, v), 0.00943887047f);
    p = __fadd_rn(__fmul_rn(p, v), 1.00167406f);
    p = __fadd_rn(__fmul_rn(p, v), 2.83297682f);
  }
  return __fmul_rn(p, x);
}

__device__ __forceinline__ float normal_from_bits(uint32_t bits) {
  const float MINVAL = __uint_as_float(0xBF7FFFFFu);   // nextafter(-1,0)
  float f = __uint_as_float((bits >> 9) | 0x3F800000u) - 1.0f;
  float u = __fadd_rn(__fmul_rn(f, 2.0f), MINVAL);
  u = fmaxf(MINVAL, u);
  const float SQRT2 = __uint_as_float(0x3FB504F3u);
  return __fmul_rn(SQRT2, xla_erfinv_f32(u));
}

// Persistent work-stealing kernel: each lane serially simulates walkers;
// on crossing it writes results and steals a fresh walker index, so waves
// never idle on the max-of-64 first-passage tail (E[max64]~356 vs E[T]~100).
__global__ __launch_bounds__(BLOCK, 8)
void ddm_kernel(const float* __restrict__ sv_p, const float* __restrict__ rate_p,
                const float* __restrict__ ndt_p, const float* __restrict__ thr_p,
                const float* __restrict__ noise_p, const float* __restrict__ dt_p,
                const int* __restrict__ nw_p, float* __restrict__ out) {
  __shared__ uint2 skeys[KLDS];
  for (int t = threadIdx.x; t < KLDS; t += BLOCK) {
    uint32_t a, b;
    tf2x32(0u, 0u, 0u, (uint32_t)t, a, b);
    skeys[t] = make_uint2(a, b);
  }
  __syncthreads();

  int nw = *nw_p;
  float sv = *sv_p, rate = *rate_p, ndt = *ndt_p, thr = *thr_p,
        noise = *noise_p, dt = *dt_p;
  float rate_dt = __fmul_rn(rate, dt);
  float sqrt_dt = __fsqrt_rn(dt);

  int i = blockIdx.x * BLOCK + threadIdx.x;   // static walker
  uint32_t home = (uint32_t)blockIdx.x & (NCTR - 1);
  bool have = (i < nw);
  bool can_grab = true;
  float p = __fadd_rn(0.0f, sv);
  float rts = 0.0f;
  int t = 0;

  while (__ballot(have) != 0ull) {
    if (have) {
      rts = __fadd_rn(rts, 1.0f);
      uint2 k;
      if (t < KLDS) {
        k = skeys[t];
      } else {               // ~1e-11 of steps: recompute key inline
        uint32_t a, b;
        tf2x32(0u, 0u, 0u, (uint32_t)t, a, b);
        k = make_uint2(a, b);
      }
      uint32_t b1, b2;
      tf2x32(k.x, k.y, 0u, (uint32_t)i, b1, b2);
      float z = normal_from_bits(b1 ^ b2);
      p = __fadd_rn(p, __fmul_rn(__fadd_rn(rate_dt, __fmul_rn(noise, z)), sqrt_dt));
      ++t;
      if (!(fabsf(p) < thr) || t >= NSTEPS) {
        out[i] = __fadd_rn(ndt, __fmul_rn(rts, dt));
        out[nw + i] = (p <= -thr) ? 0.0f : 1.0f;
        have = false;
      }
    }
    if (!have && can_grab) {
      // Steal: load-before-atomic keeps the exhaustion scan atomic-free;
      // counters are monotone so stale (low) loads are safe — the
      // atomicAdd return value is authoritative.
      for (int probe = 0; probe < NCTR; ++probe) {
        uint32_t c = (home + probe) & (NCTR - 1);
        uint32_t* ctr = &g_ctrs[c * CTR_STRIDE];
        if (__hip_atomic_load(ctr, __ATOMIC_RELAXED, __HIP_MEMORY_SCOPE_AGENT)
            >= (uint32_t)SUBRANGE) continue;
        uint32_t old = atomicAdd(ctr, 1u);
        if (old < (uint32_t)SUBRANGE) {
          int ni = NSTATIC + (int)(c * SUBRANGE + old);
          if (ni < nw) {
            i = ni; p = __fadd_rn(0.0f, sv); rts = 0.0f; t = 0; have = true;
            break;
          }
        }
      }
      if (!have) can_grab = false;   // latch: never re-probe
    }
  }
}

extern "C" void kernel_launch(void* const* d_in, const int* in_sizes, int n_in,
                              void* d_out, int out_size, void* d_ws, size_t ws_size,
                              hipStream_t stream) {
  const float* sv    = (const float*)d_in[0];
  const float* rate  = (const float*)d_in[1];
  const float* ndt   = (const float*)d_in[2];
  const float* thr   = (const float*)d_in[3];
  const float* noise = (const float*)d_in[4];
  const float* dt    = (const float*)d_in[5];
  const int*   nw    = (const int*)d_in[6];
  float* out = (float*)d_out;

  init_ctrs_kernel<<<1, NCTR, 0, stream>>>();
  ddm_kernel<<<NBLOCKS, BLOCK, 0, stream>>>(sv, rate, ndt, thr, noise, dt, nw, out);
}

// Round 5
// 1065.090 us; speedup vs baseline: 2.4729x; 2.4729x over previous
//
#include <hip/hip_runtime.h>
#include <math.h>

#define NSTEPS 3000
#define NWALK  1048576
#define BLOCK  256
#define NB     2048          // grid blocks per round; grid-stride handles any count
#define MAXC   952           // largest chunk (final round 2048->3000)
#define NROUNDS 19

// Ping-pong survivor lists (i, p-bits) + per-round survivor counts.
__device__ uint2    g_list[2][NWALK];    // 16 MB static
__device__ uint32_t g_cnt[NROUNDS + 1];

__global__ void init_kernel() {
  if (threadIdx.x < NROUNDS + 1) g_cnt[threadIdx.x] = 0u;
}

// Threefry-2x32, 20 rounds, exactly JAX's schedule.
__device__ __forceinline__ void tf2x32(uint32_t k0, uint32_t k1,
                                       uint32_t x0, uint32_t x1,
                                       uint32_t& o0, uint32_t& o1) {
  uint32_t ks2 = k0 ^ k1 ^ 0x1BD11BDAu;
  x0 += k0; x1 += k1;
#define TFR(r) { x0 += x1; x1 = (x1 << r) | (x1 >> (32 - r)); x1 ^= x0; }
  TFR(13) TFR(15) TFR(26) TFR(6)
  x0 += k1;  x1 += ks2 + 1u;
  TFR(17) TFR(29) TFR(16) TFR(24)
  x0 += ks2; x1 += k0 + 2u;
  TFR(13) TFR(15) TFR(26) TFR(6)
  x0 += k0;  x1 += k1 + 3u;
  TFR(17) TFR(29) TFR(16) TFR(24)
  x0 += k1;  x1 += ks2 + 4u;
  TFR(13) TFR(15) TFR(26) TFR(6)
  x0 += ks2; x1 += k0 + 5u;
#undef TFR
  o0 = x0; o1 = x1;
}

// XLA CPU's log.f32 (Cephes/Eigen-3.3 plog), strict f32 mul/add, no FMA.
// Bit-exact vs reference (verified R3/R4: absmax 0.094 << 0.259).
__device__ __forceinline__ float xla_cpu_log_f32(float s) {
  uint32_t bits = __float_as_uint(s);
  int emm0 = (int)(bits >> 23) - 0x7f;
  float e = __fadd_rn((float)emm0, 1.0f);
  float m = __uint_as_float((bits & 0x007fffffu) | 0x3f000000u);
  bool mlt = m < 0.70710677f;
  float tmp = mlt ? m : 0.0f;
  float x = __fsub_rn(m, 1.0f);
  e = __fsub_rn(e, mlt ? 1.0f : 0.0f);
  x = __fadd_rn(x, tmp);
  float x2 = __fmul_rn(x, x);
  float x3 = __fmul_rn(x2, x);
  float y, y1, y2;
  y  = __fadd_rn(__fmul_rn(7.0376836292e-2f,  x), -1.1514610310e-1f);
  y1 = __fadd_rn(__fmul_rn(-1.2420140846e-1f, x),  1.4249322787e-1f);
  y2 = __fadd_rn(__fmul_rn(2.0000714765e-1f,  x), -2.4999993993e-1f);
  y  = __fadd_rn(__fmul_rn(y,  x),  1.1676998740e-1f);
  y1 = __fadd_rn(__fmul_rn(y1, x), -1.6668057665e-1f);
  y2 = __fadd_rn(__fmul_rn(y2, x),  3.3333331174e-1f);
  y  = __fadd_rn(__fmul_rn(y, x3), y1);
  y  = __fadd_rn(__fmul_rn(y, x3), y2);
  y  = __fmul_rn(y, x3);
  y1 = __fmul_rn(e, -2.12194440e-4f);
  tmp = __fmul_rn(x2, 0.5f);
  y  = __fadd_rn(y, y1);
  x  = __fsub_rn(x, tmp);
  y2 = __fmul_rn(e, 0.693359375f);
  x  = __fadd_rn(x, y);
  x  = __fadd_rn(x, y2);
  return x;
}

// XLA EmitErfInv f32 (Giles): w = -log((1-x)*(1+x)), branch at w<5.
__device__ __forceinline__ float xla_erfinv_f32(float x) {
  float s = __fmul_rn(__fsub_rn(1.0f, x), __fadd_rn(1.0f, x));
  float w = -xla_cpu_log_f32(s);
  float p;
  if (w < 5.0f) {
    float v = __fsub_rn(w, 2.5f);
    p = 2.81022636e-08f;
    p = __fadd_rn(__fmul_rn(p, v), 3.43273939e-07f);
    p = __fadd_rn(__fmul_rn(p, v), -3.5233877e-06f);
    p = __fadd_rn(__fmul_rn(p, v), -4.39150654e-06f);
    p = __fadd_rn(__fmul_rn(p, v), 0.00021858087f);
    p = __fadd_rn(__fmul_rn(p, v), -0.00125372503f);
    p = __fadd_rn(__fmul_rn(p, v), -0.00417768164f);
    p = __fadd_rn(__fmul_rn(p, v), 0.246640727f);
    p = __fadd_rn(__fmul_rn(p, v), 1.50140941f);
  } else {
    float v = __fsub_rn(__fsqrt_rn(w), 3.0f);
    p = -0.000200214257f;
    p = __fadd_rn(__fmul_rn(p, v), 0.000100950558f);
    p = __fadd_rn(__fmul_rn(p, v), 0.00134934322f);
    p = __fadd_rn(__fmul_rn(p, v), -0.00367342844f);
    p = __fadd_rn(__fmul_rn(p, v), 0.00573950773f);
    p = __fadd_rn(__fmul_rn(p, v), -0.0076224613f);
    p = __fadd_rn(__fmul_rn(p, v), 0.00943887047f);
    p = __fadd_rn(__fmul_rn(p, v), 1.00167406f);
    p = __fadd_rn(__fmul_rn(p, v), 2.83297682f);
  }
  return __fmul_rn(p, x);
}

__device__ __forceinline__ float normal_from_bits(uint32_t bits) {
  const float MINVAL = __uint_as_float(0xBF7FFFFFu);   // nextafter(-1,0)
  float f = __uint_as_float((bits >> 9) | 0x3F800000u) - 1.0f;
  float u = __fadd_rn(__fmul_rn(f, 2.0f), MINVAL);
  u = fmaxf(MINVAL, u);
  const float SQRT2 = __uint_as_float(0x3FB504F3u);
  return __fmul_rn(SQRT2, xla_erfinv_f32(u));
}

// One compaction round: simulate chunk [t0,t1); all lanes share t (broadcast
// LDS key reads, dense inner loop identical to the R3 90%-VALUBusy kernel).
// Crossers write outputs and die; survivors are wave-aggregated-appended
// (one atomic per wave) to the next round's list.
__global__ __launch_bounds__(BLOCK)
void ddm_round(const float* __restrict__ sv_p, const float* __restrict__ rate_p,
               const float* __restrict__ ndt_p, const float* __restrict__ thr_p,
               const float* __restrict__ noise_p, const float* __restrict__ dt_p,
               const int* __restrict__ nw_p, float* __restrict__ out,
               int round, int t0, int t1) {
  const int C = t1 - t0;
  __shared__ uint2 skeys[MAXC];
  for (int s = threadIdx.x; s < C; s += BLOCK) {
    uint32_t a, b;
    tf2x32(0u, 0u, 0u, (uint32_t)(t0 + s), a, b);
    skeys[s] = make_uint2(a, b);
  }
  __syncthreads();

  int nw = *nw_p;
  float sv = *sv_p, rate = *rate_p, ndt = *ndt_p, thr = *thr_p,
        noise = *noise_p, dt = *dt_p;
  float rate_dt = __fmul_rn(rate, dt);
  float sqrt_dt = __fsqrt_rn(dt);

  uint32_t count = (round == 0) ? (uint32_t)nw : g_cnt[round];
  const uint32_t G = (uint32_t)gridDim.x * BLOCK;
  int lane = threadIdx.x & 63;

  for (uint32_t slot = blockIdx.x * BLOCK + threadIdx.x; ; slot += G) {
    bool haveslot = slot < count;
    if (__ballot(haveslot) == 0ull) break;   // whole wave out of work

    int i = 0; float p = 0.0f;
    bool alive = haveslot;
    if (haveslot) {
      if (round == 0) { i = (int)slot; p = __fadd_rn(0.0f, sv); }
      else { uint2 e = g_list[round & 1][slot]; i = (int)e.x; p = __uint_as_float(e.y); }
    }

    for (int s = 0; s < C; ++s) {
      if (__ballot(alive) == 0ull) break;    // all 64 walkers done this chunk
      if (alive) {
        uint2 k = skeys[s];                  // uniform t: broadcast, no conflicts
        uint32_t b1, b2;
        tf2x32(k.x, k.y, 0u, (uint32_t)i, b1, b2);
        float z = normal_from_bits(b1 ^ b2);
        p = __fadd_rn(p, __fmul_rn(__fadd_rn(rate_dt, __fmul_rn(noise, z)), sqrt_dt));
        if (!(fabsf(p) < thr)) {             // crossed: rts_count = global_t + 1
          float rts = (float)(t0 + s + 1);   // exact integer, == accumulated +1.0f
          out[i] = __fadd_rn(ndt, __fmul_rn(rts, dt));
          out[nw + i] = (p <= -thr) ? 0.0f : 1.0f;
          alive = false;
        }
      }
    }

    if (t1 >= NSTEPS) {
      if (alive) {                           // ran out the clock: rts = 3000
        out[i] = __fadd_rn(ndt, __fmul_rn((float)NSTEPS, dt));
        out[nw + i] = (p <= -thr) ? 0.0f : 1.0f;
      }
    } else {
      uint64_t m = __ballot(alive);
      if (m != 0ull) {                       // one atomic per wave
        int leader = __ffsll((unsigned long long)m) - 1;
        uint32_t base = 0;
        if (lane == leader) base = atomicAdd(&g_cnt[round + 1], (uint32_t)__popcll(m));
        base = (uint32_t)__shfl((int)base, leader);
        if (alive) {
          uint32_t pos = base + (uint32_t)__popcll(m & ((1ull << lane) - 1ull));
          g_list[(round + 1) & 1][pos] = make_uint2((uint32_t)i, __float_as_uint(p));
        }
      }
    }
  }
}

extern "C" void kernel_launch(void* const* d_in, const int* in_sizes, int n_in,
                              void* d_out, int out_size, void* d_ws, size_t ws_size,
                              hipStream_t stream) {
  const float* sv    = (const float*)d_in[0];
  const float* rate  = (const float*)d_in[1];
  const float* ndt   = (const float*)d_in[2];
  const float* thr   = (const float*)d_in[3];
  const float* noise = (const float*)d_in[4];
  const float* dt    = (const float*)d_in[5];
  const int*   nw    = (const int*)d_in[6];
  float* out = (float*)d_out;

  // Chunk schedule: fine (64) where most walkers live, coarse where few do.
  static const int tb[NROUNDS + 1] = {0, 64, 128, 192, 256, 320, 384, 448, 512,
                                      576, 640, 768, 896, 1024, 1152, 1280,
                                      1536, 1792, 2048, 3000};
  init_kernel<<<1, 64, 0, stream>>>();
  for (int r = 0; r < NROUNDS; ++r) {
    ddm_round<<<NB, BLOCK, 0, stream>>>(sv, rate, ndt, thr, noise, dt, nw, out,
                                        r, tb[r], tb[r + 1]);
  }
}

// Round 6
// 811.417 us; speedup vs baseline: 3.2460x; 1.3126x over previous
//
#include <hip/hip_runtime.h>
#include <math.h>

#define NSTEPS 3000
#define NWALK  1048576
#define BLOCK  256
#define NBD    (NWALK / BLOCK)   // 4096 dense blocks: one slot per lane
#define NDENSE 6                 // dense rounds cover t in [0, 384)
#define CHUNK  64
#define NBT    2048              // tail grid: 8192 waves
#define NKEYS  3072

// Ping-pong survivor lists (i, p-bits), per-round counts, precomputed keys.
__device__ uint2    g_list[2][NWALK];
__device__ uint32_t g_cnt[8];
__device__ uint2    g_keys[NKEYS];

// Threefry-2x32, 20 rounds, exactly JAX's schedule.
__device__ __forceinline__ void tf2x32(uint32_t k0, uint32_t k1,
                                       uint32_t x0, uint32_t x1,
                                       uint32_t& o0, uint32_t& o1) {
  uint32_t ks2 = k0 ^ k1 ^ 0x1BD11BDAu;
  x0 += k0; x1 += k1;
#define TFR(r) { x0 += x1; x1 = (x1 << r) | (x1 >> (32 - r)); x1 ^= x0; }
  TFR(13) TFR(15) TFR(26) TFR(6)
  x0 += k1;  x1 += ks2 + 1u;
  TFR(17) TFR(29) TFR(16) TFR(24)
  x0 += ks2; x1 += k0 + 2u;
  TFR(13) TFR(15) TFR(26) TFR(6)
  x0 += k0;  x1 += k1 + 3u;
  TFR(17) TFR(29) TFR(16) TFR(24)
  x0 += k1;  x1 += ks2 + 4u;
  TFR(13) TFR(15) TFR(26) TFR(6)
  x0 += ks2; x1 += k0 + 5u;
#undef TFR
  o0 = x0; o1 = x1;
}

// init: per-step folded split keys (counter (0,t), key (0,0)) + zero counts.
__global__ void init_kernel() {   // <<<NKEYS/256, 256>>>
  int t = blockIdx.x * 256 + threadIdx.x;
  uint32_t a, b;
  tf2x32(0u, 0u, 0u, (uint32_t)t, a, b);
  g_keys[t] = make_uint2(a, b);
  if (blockIdx.x == 0 && threadIdx.x < 8) g_cnt[threadIdx.x] = 0u;
}

// XLA CPU's log.f32 (Cephes/Eigen-3.3 plog), strict f32 mul/add, no FMA.
// Bit-exact vs reference (verified R3/R4/R5: absmax 0.094 << 0.259).
__device__ __forceinline__ float xla_cpu_log_f32(float s) {
  uint32_t bits = __float_as_uint(s);
  int emm0 = (int)(bits >> 23) - 0x7f;
  float e = __fadd_rn((float)emm0, 1.0f);
  float m = __uint_as_float((bits & 0x007fffffu) | 0x3f000000u);
  bool mlt = m < 0.70710677f;
  float tmp = mlt ? m : 0.0f;
  float x = __fsub_rn(m, 1.0f);
  e = __fsub_rn(e, mlt ? 1.0f : 0.0f);
  x = __fadd_rn(x, tmp);
  float x2 = __fmul_rn(x, x);
  float x3 = __fmul_rn(x2, x);
  float y, y1, y2;
  y  = __fadd_rn(__fmul_rn(7.0376836292e-2f,  x), -1.1514610310e-1f);
  y1 = __fadd_rn(__fmul_rn(-1.2420140846e-1f, x),  1.4249322787e-1f);
  y2 = __fadd_rn(__fmul_rn(2.0000714765e-1f,  x), -2.4999993993e-1f);
  y  = __fadd_rn(__fmul_rn(y,  x),  1.1676998740e-1f);
  y1 = __fadd_rn(__fmul_rn(y1, x), -1.6668057665e-1f);
  y2 = __fadd_rn(__fmul_rn(y2, x),  3.3333331174e-1f);
  y  = __fadd_rn(__fmul_rn(y, x3), y1);
  y  = __fadd_rn(__fmul_rn(y, x3), y2);
  y  = __fmul_rn(y, x3);
  y1 = __fmul_rn(e, -2.12194440e-4f);
  tmp = __fmul_rn(x2, 0.5f);
  y  = __fadd_rn(y, y1);
  x  = __fsub_rn(x, tmp);
  y2 = __fmul_rn(e, 0.693359375f);
  x  = __fadd_rn(x, y);
  x  = __fadd_rn(x, y2);
  return x;
}

// XLA EmitErfInv f32 (Giles): w = -log((1-x)*(1+x)), branch at w<5.
__device__ __forceinline__ float xla_erfinv_f32(float x) {
  float s = __fmul_rn(__fsub_rn(1.0f, x), __fadd_rn(1.0f, x));
  float w = -xla_cpu_log_f32(s);
  float p;
  if (w < 5.0f) {
    float v = __fsub_rn(w, 2.5f);
    p = 2.81022636e-08f;
    p = __fadd_rn(__fmul_rn(p, v), 3.43273939e-07f);
    p = __fadd_rn(__fmul_rn(p, v), -3.5233877e-06f);
    p = __fadd_rn(__fmul_rn(p, v), -4.39150654e-06f);
    p = __fadd_rn(__fmul_rn(p, v), 0.00021858087f);
    p = __fadd_rn(__fmul_rn(p, v), -0.00125372503f);
    p = __fadd_rn(__fmul_rn(p, v), -0.00417768164f);
    p = __fadd_rn(__fmul_rn(p, v), 0.246640727f);
    p = __fadd_rn(__fmul_rn(p, v), 1.50140941f);
  } else {
    float v = __fsub_rn(__fsqrt_rn(w), 3.0f);
    p = -0.000200214257f;
    p = __fadd_rn(__fmul_rn(p, v), 0.000100950558f);
    p = __fadd_rn(__fmul_rn(p, v), 0.00134934322f);
    p = __fadd_rn(__fmul_rn(p, v), -0.00367342844f);
    p = __fadd_rn(__fmul_rn(p, v), 0.00573950773f);
    p = __fadd_rn(__fmul_rn(p, v), -0.0076224613f);
    p = __fadd_rn(__fmul_rn(p, v), 0.00943887047f);
    p = __fadd_rn(__fmul_rn(p, v), 1.00167406f);
    p = __fadd_rn(__fmul_rn(p, v), 2.83297682f);
  }
  return __fmul_rn(p, x);
}

__device__ __forceinline__ float normal_from_bits(uint32_t bits) {
  const float MINVAL = __uint_as_float(0xBF7FFFFFu);   // nextafter(-1,0)
  float f = __uint_as_float((bits >> 9) | 0x3F800000u) - 1.0f;
  float u = __fadd_rn(__fmul_rn(f, 2.0f), MINVAL);
  u = fmaxf(MINVAL, u);
  const float SQRT2 = __uint_as_float(0x3FB504F3u);
  return __fmul_rn(SQRT2, xla_erfinv_f32(u));
}

// Dense compaction round: one walker slot per lane, chunk [t0,t0+64).
// Crossers write outputs and die; survivors wave-aggregated into next list.
__global__ __launch_bounds__(BLOCK)
void ddm_round(const float* __restrict__ sv_p, const float* __restrict__ rate_p,
               const float* __restrict__ ndt_p, const float* __restrict__ thr_p,
               const float* __restrict__ noise_p, const float* __restrict__ dt_p,
               const int* __restrict__ nw_p, float* __restrict__ out,
               int round, int t0) {
  __shared__ uint2 skeys[CHUNK];
  if (threadIdx.x < CHUNK) {
    uint32_t a, b;
    tf2x32(0u, 0u, 0u, (uint32_t)(t0 + threadIdx.x), a, b);
    skeys[threadIdx.x] = make_uint2(a, b);
  }
  __syncthreads();

  int nw = *nw_p;
  uint32_t count = (round == 0) ? (uint32_t)nw : g_cnt[round];
  uint32_t slot = blockIdx.x * BLOCK + threadIdx.x;
  bool alive = slot < count;
  if (__ballot(alive) == 0ull) return;      // wave fully out of range

  float sv = *sv_p, rate = *rate_p, ndt = *ndt_p, thr = *thr_p,
        noise = *noise_p, dt = *dt_p;
  float rate_dt = __fmul_rn(rate, dt);
  float sqrt_dt = __fsqrt_rn(dt);
  int lane = threadIdx.x & 63;

  int i = 0; float p = 0.0f;
  if (alive) {
    if (round == 0) { i = (int)slot; p = __fadd_rn(0.0f, sv); }
    else { uint2 e = g_list[round & 1][slot]; i = (int)e.x; p = __uint_as_float(e.y); }
  }

  for (int s = 0; s < CHUNK; ++s) {
    if (alive) {
      uint2 k = skeys[s];                   // uniform s: broadcast, no conflicts
      uint32_t b1, b2;
      tf2x32(k.x, k.y, 0u, (uint32_t)i, b1, b2);
      float z = normal_from_bits(b1 ^ b2);
      p = __fadd_rn(p, __fmul_rn(__fadd_rn(rate_dt, __fmul_rn(noise, z)), sqrt_dt));
      if (!(fabsf(p) < thr)) {
        float rts = (float)(t0 + s + 1);    // exact int == accumulated +1.0f
        out[i] = __fadd_rn(ndt, __fmul_rn(rts, dt));
        out[nw + i] = (p <= -thr) ? 0.0f : 1.0f;
        alive = false;
      }
    }
  }

  uint64_t m = __ballot(alive);
  if (m != 0ull) {                          // one atomic per wave
    int leader = __ffsll((unsigned long long)m) - 1;
    uint32_t base = 0;
    if (lane == leader) base = atomicAdd(&g_cnt[round + 1], (uint32_t)__popcll(m));
    base = (uint32_t)__shfl((int)base, leader);
    if (alive) {
      uint32_t pos = base + (uint32_t)__popcll(m & ((1ull << lane) - 1ull));
      g_list[(round + 1) & 1][pos] = make_uint2((uint32_t)i, __float_as_uint(p));
    }
  }
}

// Tail: ONE WALKER PER WAVE. z_t is counter-based (depends only on (t,i)), so
// 64 lanes compute q_{t..t+63} in parallel (bit-identical op sequence), then a
// wave-uniform serial scan (exact fadd order) advances the walker 64 steps in
// ~1.2K cycles — kills both the dense dead-lane waste and the single-wave
// latency floor of the deep-tail rounds.
__global__ __launch_bounds__(BLOCK)
void ddm_tail(const float* __restrict__ sv_p, const float* __restrict__ rate_p,
              const float* __restrict__ ndt_p, const float* __restrict__ thr_p,
              const float* __restrict__ noise_p, const float* __restrict__ dt_p,
              const int* __restrict__ nw_p, float* __restrict__ out,
              int round, int t0) {
  int nw = *nw_p;
  float rate = *rate_p, ndt = *ndt_p, thr = *thr_p,
        noise = *noise_p, dt = *dt_p;
  float rate_dt = __fmul_rn(rate, dt);
  float sqrt_dt = __fsqrt_rn(dt);

  int lane = threadIdx.x & 63;
  uint32_t wave = blockIdx.x * (BLOCK / 64) + (threadIdx.x >> 6);
  uint32_t nwaves = gridDim.x * (BLOCK / 64);
  uint32_t count = g_cnt[round];

  for (uint32_t k = wave; k < count; k += nwaves) {
    uint2 e = g_list[round & 1][k];
    int i = (int)e.x;
    float p = __uint_as_float(e.y);        // wave-uniform from here on
    int t = t0;
    int rts_i = NSTEPS;
    bool done = false;
    while (!done) {
      int valid = NSTEPS - t; if (valid > 64) valid = 64;
      int tl = t + (lane < valid ? lane : valid - 1);
      uint2 kk = g_keys[tl];               // coalesced 8B, L2-resident
      uint32_t b1, b2;
      tf2x32(kk.x, kk.y, 0u, (uint32_t)i, b1, b2);
      float z = normal_from_bits(b1 ^ b2);
      float q = __fmul_rn(__fadd_rn(rate_dt, __fmul_rn(noise, z)), sqrt_dt);
      for (int j = 0; j < valid; ++j) {    // exact sequential scan
        float qj = __shfl(q, j);
        p = __fadd_rn(p, qj);
        if (!(fabsf(p) < thr)) { rts_i = t + j + 1; done = true; break; }
      }
      if (!done) {
        t += valid;
        if (t >= NSTEPS) done = true;      // ran out the clock: rts = 3000
      }
    }
    if (lane == 0) {
      out[i] = __fadd_rn(ndt, __fmul_rn((float)rts_i, dt));
      out[nw + i] = (p <= -thr) ? 0.0f : 1.0f;
    }
  }
}

extern "C" void kernel_launch(void* const* d_in, const int* in_sizes, int n_in,
                              void* d_out, int out_size, void* d_ws, size_t ws_size,
                              hipStream_t stream) {
  const float* sv    = (const float*)d_in[0];
  const float* rate  = (const float*)d_in[1];
  const float* ndt   = (const float*)d_in[2];
  const float* thr   = (const float*)d_in[3];
  const float* noise = (const float*)d_in[4];
  const float* dt    = (const float*)d_in[5];
  const int*   nw    = (const int*)d_in[6];
  float* out = (float*)d_out;

  init_kernel<<<NKEYS / 256, 256, 0, stream>>>();
  for (int r = 0; r < NDENSE; ++r) {
    ddm_round<<<NBD, BLOCK, 0, stream>>>(sv, rate, ndt, thr, noise, dt, nw, out,
                                         r, r * CHUNK);
  }
  ddm_tail<<<NBT, BLOCK, 0, stream>>>(sv, rate, ndt, thr, noise, dt, nw, out,
                                      NDENSE, NDENSE * CHUNK);
}